// Round 13
// baseline (60.245 us; speedup 1.0000x reference)
//
#include <hip/hip_runtime.h>
#include <math.h>

#define BB 8192
#define DD 4096
#define EE 64

constexpr float NOISE_EPS = 0.01f;
constexpr int BM = 32;              // rows per block (main GEMM)

typedef __attribute__((ext_vector_type(8))) _Float16 f16x8;
typedef __attribute__((ext_vector_type(4))) float    f32x4;

__device__ __forceinline__ void split8(const float4& a, const float4& b,
                                       f16x8& hi, f16x8& mi) {
    float v[8] = {a.x, a.y, a.z, a.w, b.x, b.y, b.z, b.w};
    #pragma unroll
    for (int j = 0; j < 8; ++j) {
        _Float16 h = (_Float16)v[j];          // RN
        hi[j] = h;
        mi[j] = (_Float16)(v[j] - (float)h);
    }
}

// ---- pre-pass: pack weights into fp16 hi/mid planes in FRAGMENT order ----
// wpk chunk T (16 KB, T = global 32-k chunk): [cb 0..7][plane 0..1][lane 0..63] x 16B
// content(cb,p,lane): 8 fp16, weight row cb*16+(lane&15), k = T*32+(lane>>4)*8..
__global__ __launch_bounds__(256) void wsplit_pack(
    const float* __restrict__ gw, const float* __restrict__ ngw,
    char* __restrict__ wpk)
{
    const int gid = blockIdx.x * 256 + threadIdx.x;   // 65536 threads
    const int r   = gid >> 9;                         // 0..127
    const int kc  = gid & 511;                        // 8-float chunk in row
    const int k0  = kc * 8;
    const float* src = (r < EE) ? gw + (size_t)r * DD + k0
                                : ngw + (size_t)(r - EE) * DD + k0;
    float4 a = *reinterpret_cast<const float4*>(src);
    float4 b = *reinterpret_cast<const float4*>(src + 4);
    f16x8 hi, mi;
    split8(a, b, hi, mi);
    const int T    = k0 >> 5;
    const int kq   = (k0 >> 3) & 3;
    const int cb   = r >> 4;
    const int lane = kq * 16 + (r & 15);
    char* base = wpk + (size_t)T * 16384;
    *reinterpret_cast<f16x8*>(base + ((cb * 2 + 0) * 64 + lane) * 16) = hi;
    *reinterpret_cast<f16x8*>(base + ((cb * 2 + 1) * 64 + lane) * 16) = mi;
}

// ------------------------------- main GEMM --------------------------------
// DRAM-page-friendly staging: macro-step = 256 k -> each row contributes a
// 1 KB CONTIGUOUS burst per stage (each thread 64 B contiguous), rows stream
// sequentially across macro-steps. x split once to fp16 hi/mi planes in a
// swizzled LDS tile (2-way-free ds_read_b128). 8 waves = 8 col-blocks: every
// B chunk read exactly once per block, straight from frag-packed global (L2).
// One lgkmcnt+barrier per macro-step; all global loads compiler-counted.
template <int SK>
__global__ __launch_bounds__(512, 4) void gating_main(
    const float* __restrict__ x,
    const char*  __restrict__ wpk,
    float* __restrict__ partial)       // [SK][BB][128]
{
    constexpr int KC   = DD / SK;       // 2048 for SK=2
    constexpr int NMS  = KC / 256;      // macro-steps (8 for SK=2)
    constexpr int GMAX = KC / 32 - 1;   // last local 32-k chunk index

    // [buf][row 0..31][plane hi|mi][32 swizzled 16B slots] = 2 x 32 KB
    __shared__ __align__(1024) char xls[2][32768];

    const int tid  = threadIdx.x;
    const int bid  = blockIdx.x;
    const int sk   = bid & (SK - 1);
    const int row0 = (bid / SK) * BM;
    const int lane = tid & 63;
    const int wv   = tid >> 6;          // wave = col-block cb (0..7)
    const int l15  = lane & 15;
    const int kq   = lane >> 4;

    // ---- x staging: thread -> (row sr, 16-float contiguous seg ss) ----
    const int sr = tid >> 4;            // 0..31
    const int ss = tid & 15;            // 0..15
    const float* xg = x + (size_t)(row0 + sr) * DD + sk * KC + ss * 16;
    const int swr = sr & 7;
    const int wo_h0 = sr * 1024 +       (((2 * ss)     ^ swr) << 4);
    const int wo_h1 = sr * 1024 +       (((2 * ss + 1) ^ swr) << 4);
    const int wo_m0 = sr * 1024 + 512 + (((2 * ss)     ^ swr) << 4);
    const int wo_m1 = sr * 1024 + 512 + (((2 * ss + 1) ^ swr) << 4);

    // ---- A-frag read bases: m-tile m rows m*16+l15 ----
    const int rb0 = (l15) * 1024,      swz0 = l15 & 7;
    const int rb1 = (16 + l15) * 1024, swz1 = (16 + l15) & 7;

    // ---- B: this wave's 2 KB slice (cb=wv) of each 16 KB packed chunk ----
    const char* wpkB = wpk + ((size_t)(sk * (KC / 32)) << 14)
                           + wv * 2048 + lane * 16;

    f32x4 acc0 = {0.f, 0.f, 0.f, 0.f};
    f32x4 acc1 = {0.f, 0.f, 0.f, 0.f};

    #define LOADB(g, H, M) do {                                                \
        const char* _b = wpkB + ((size_t)(g) << 14);                           \
        H = *reinterpret_cast<const f16x8*>(_b);                               \
        M = *reinterpret_cast<const f16x8*>(_b + 1024);                        \
    } while (0)

    #define LOADX(t) do {                                                      \
        const float* _s = xg + (size_t)(t) * 256;                              \
        xa0 = *reinterpret_cast<const float4*>(_s);                            \
        xa1 = *reinterpret_cast<const float4*>(_s + 4);                        \
        xa2 = *reinterpret_cast<const float4*>(_s + 8);                        \
        xa3 = *reinterpret_cast<const float4*>(_s + 12);                       \
    } while (0)

    #define WSPLIT(bp) do {                                                    \
        f16x8 _h, _m;                                                          \
        split8(xa0, xa1, _h, _m);                                              \
        *reinterpret_cast<f16x8*>((bp) + wo_h0) = _h;                          \
        *reinterpret_cast<f16x8*>((bp) + wo_m0) = _m;                          \
        split8(xa2, xa3, _h, _m);                                              \
        *reinterpret_cast<f16x8*>((bp) + wo_h1) = _h;                          \
        *reinterpret_cast<f16x8*>((bp) + wo_m1) = _m;                          \
    } while (0)

    // one 32-k chunk: 4 ds_read_b128 + 6 MFMA + JIT B reload (2 chunks ahead)
    #define CHUNK(c, H, M) do {                                                \
        const int _s0 = (((c) * 4 + kq) ^ swz0) << 4;                          \
        const int _s1 = (((c) * 4 + kq) ^ swz1) << 4;                          \
        f16x8 ah0 = *reinterpret_cast<const f16x8*>(bufc + rb0 + _s0);         \
        f16x8 am0 = *reinterpret_cast<const f16x8*>(bufc + rb0 + 512 + _s0);   \
        f16x8 ah1 = *reinterpret_cast<const f16x8*>(bufc + rb1 + _s1);         \
        f16x8 am1 = *reinterpret_cast<const f16x8*>(bufc + rb1 + 512 + _s1);   \
        acc0 = __builtin_amdgcn_mfma_f32_16x16x32_f16(ah0, H, acc0, 0, 0, 0);  \
        acc1 = __builtin_amdgcn_mfma_f32_16x16x32_f16(ah1, H, acc1, 0, 0, 0);  \
        acc0 = __builtin_amdgcn_mfma_f32_16x16x32_f16(am0, H, acc0, 0, 0, 0);  \
        acc1 = __builtin_amdgcn_mfma_f32_16x16x32_f16(am1, H, acc1, 0, 0, 0);  \
        acc0 = __builtin_amdgcn_mfma_f32_16x16x32_f16(ah0, M, acc0, 0, 0, 0);  \
        acc1 = __builtin_amdgcn_mfma_f32_16x16x32_f16(ah1, M, acc1, 0, 0, 0);  \
        { const int _g = gbase + (c) + 2;                                      \
          LOADB((_g <= GMAX) ? _g : GMAX, H, M); }                             \
    } while (0)

    float4 xa0, xa1, xa2, xa3;
    f16x8 pH, pM, qH, qM;

    // ---- prologue: x(0) -> buf0 ; B chunks 0,1 -> regs ----
    LOADX(0);
    WSPLIT(xls[0]);
    LOADB(0, pH, pM);
    LOADB(1, qH, qM);

    // ---- main loop: 1 lgkmcnt + 1 barrier per macro-step ----
    for (int t = 0; t < NMS; ++t) {
        asm volatile("s_waitcnt lgkmcnt(0)" ::: "memory");
        __builtin_amdgcn_s_barrier();

        if (t + 1 < NMS) LOADX(t + 1);      // 64 B contiguous per thread

        const char* bufc = xls[t & 1];
        const int gbase = t * 8;
        CHUNK(0, pH, pM);
        CHUNK(1, qH, qM);
        CHUNK(2, pH, pM);
        CHUNK(3, qH, qM);
        CHUNK(4, pH, pM);
        CHUNK(5, qH, qM);
        CHUNK(6, pH, pM);
        CHUNK(7, qH, qM);

        if (t + 1 < NMS) WSPLIT(xls[(t + 1) & 1]);
    }

    #undef LOADB
    #undef LOADX
    #undef WSPLIT
    #undef CHUNK

    // ---- partial logits out (deterministic, no atomics) ----
    const size_t pbase = ((size_t)sk * BB + row0) * 128;
    #pragma unroll
    for (int j = 0; j < 4; ++j) {
        const int r0 = kq * 4 + j;
        const int c  = wv * 16 + l15;
        partial[pbase + (size_t)r0 * 128 + c]        = acc0[j];
        partial[pbase + (size_t)(r0 + 16) * 128 + c] = acc1[j];
    }
}

// ------------------------------- epilogue ---------------------------------
template <int SK>
__global__ __launch_bounds__(512) void gating_epi(
    const float* __restrict__ partial,   // [SK][BB][128]
    const float* __restrict__ noise,     // [B, E]
    float* __restrict__ out)             // gates [B,E] then load [B,E]
{
    const int tid  = threadIdx.x;
    const int wv   = tid >> 6;
    const int lane = tid & 63;
    const int l15  = lane & 15;
    const int kq   = lane >> 4;
    const int grow = blockIdx.x * 32 + wv * 4 + kq;
    const int s    = l15;                // experts 4s..4s+3

    const float* pb = partial + (size_t)grow * 128 + 4 * s;
    float4 c4 = {0.f,0.f,0.f,0.f}, n4 = {0.f,0.f,0.f,0.f};
    #pragma unroll
    for (int k = 0; k < SK; ++k) {
        const float* p = pb + (size_t)k * BB * 128;
        float4 a = *reinterpret_cast<const float4*>(p);
        float4 b = *reinterpret_cast<const float4*>(p + 64);
        c4.x += a.x; c4.y += a.y; c4.z += a.z; c4.w += a.w;
        n4.x += b.x; n4.y += b.y; n4.z += b.z; n4.w += b.w;
    }

    float4 nz = *reinterpret_cast<const float4*>(noise + (size_t)grow * EE + 4 * s);

    float cc[4] = {c4.x, c4.y, c4.z, c4.w};
    float nl[4] = {n4.x, n4.y, n4.z, n4.w};
    float m1 = -3.4e38f, m2 = -3.4e38f;
    int   i1 = -1, i2 = -1;
    float cmax = -3.4e38f;
    #pragma unroll
    for (int j = 0; j < 4; ++j) {
        const int e = 4 * s + j;
        float sp  = fmaxf(nl[j], 0.0f) + log1pf(expf(-fabsf(nl[j])));  // softplus
        float nzj = (j == 0) ? nz.x : (j == 1) ? nz.y : (j == 2) ? nz.z : nz.w;
        float vno = fmaf(nzj * sp, NOISE_EPS, cc[j]);
        if (vno > m1)      { m2 = m1; i2 = i1; m1 = vno; i1 = e; }
        else if (vno > m2) { m2 = vno; i2 = e; }
        cmax = fmaxf(cmax, cc[j]);
    }

    // 16-lane reduce: top-2 with (value, lower-index) tiebreak + clean max
    #pragma unroll
    for (int m = 1; m < 16; m <<= 1) {
        float b1 = __shfl_xor(m1, m, 16);
        int  bi1 = __shfl_xor(i1, m, 16);
        float b2 = __shfl_xor(m2, m, 16);
        int  bi2 = __shfl_xor(i2, m, 16);
        cmax = fmaxf(cmax, __shfl_xor(cmax, m, 16));

        bool bwin = (b1 > m1) || (b1 == m1 && bi1 < i1);
        float t1; int ti1; float t2; int ti2;
        if (bwin) {
            t1 = b1; ti1 = bi1;
            bool aw = (m1 > b2) || (m1 == b2 && i1 < bi2);
            t2 = aw ? m1 : b2; ti2 = aw ? i1 : bi2;
        } else {
            t1 = m1; ti1 = i1;
            bool bw = (b1 > m2) || (b1 == m2 && bi1 < i2);
            t2 = bw ? b1 : m2; ti2 = bw ? bi1 : i2;
        }
        m1 = t1; i1 = ti1; m2 = t2; i2 = ti2;
    }

    float tq = expf(m2 - m1);
    float p1 = 1.0f / (1.0f + tq);
    float p2 = tq * p1;

    float e0 = expf(cc[0] - cmax);
    float e1 = expf(cc[1] - cmax);
    float e2 = expf(cc[2] - cmax);
    float e3 = expf(cc[3] - cmax);
    float sum = e0 + e1 + e2 + e3;
    #pragma unroll
    for (int m = 1; m < 16; m <<= 1) sum += __shfl_xor(sum, m, 16);
    float inv = 1.0f / sum;

    const int eb = 4 * s;
    float4 gt;
    gt.x = (eb     == i1) ? p1 : (eb     == i2) ? p2 : 0.0f;
    gt.y = (eb + 1 == i1) ? p1 : (eb + 1 == i2) ? p2 : 0.0f;
    gt.z = (eb + 2 == i1) ? p1 : (eb + 2 == i2) ? p2 : 0.0f;
    gt.w = (eb + 3 == i1) ? p1 : (eb + 3 == i2) ? p2 : 0.0f;
    float4 ld = {e0 * inv, e1 * inv, e2 * inv, e3 * inv};

    *reinterpret_cast<float4*>(out + (size_t)grow * EE + eb) = gt;
    *reinterpret_cast<float4*>(out + (size_t)BB * EE + (size_t)grow * EE + eb) = ld;
}

extern "C" void kernel_launch(void* const* d_in, const int* in_sizes, int n_in,
                              void* d_out, int out_size, void* d_ws, size_t ws_size,
                              hipStream_t stream) {
    const float* x     = (const float*)d_in[0];
    const float* gw    = (const float*)d_in[1];
    const float* ngw   = (const float*)d_in[2];
    const float* noise = (const float*)d_in[3];
    float* out = (float*)d_out;

    char*  wpk     = (char*)d_ws;                                // 2 MB packed w
    float* partial = (float*)(wpk + (size_t)2 * 1024 * 1024);    // SK * 4 MB

    const size_t MB = 1024 * 1024;

    hipLaunchKernelGGL(wsplit_pack, dim3(256), dim3(256), 0, stream, gw, ngw, wpk);

    if (ws_size >= 11 * MB) {
        hipLaunchKernelGGL(gating_main<2>, dim3((BB / BM) * 2), dim3(512), 0, stream,
                           x, wpk, partial);
        hipLaunchKernelGGL(gating_epi<2>, dim3(BB / 32), dim3(512), 0, stream,
                           partial, noise, out);
    } else {
        hipLaunchKernelGGL(gating_main<1>, dim3(BB / BM), dim3(512), 0, stream,
                           x, wpk, partial);
        hipLaunchKernelGGL(gating_epi<1>, dim3(BB / 32), dim3(512), 0, stream,
                           partial, noise, out);
    }
}